// Round 4
// baseline (4264.054 us; speedup 1.0000x reference)
//
#include <hip/hip_runtime.h>
#include <math.h>

#define Bz 32
#define Lz 2048
#define Iz 64
#define Hz 512
#define HALFz 256
#define DTz 0.05f
#define NMEM 8
#define TPB 512

#define FMA4(P, S, W) do { (P).x = fmaf((S), (W).x, (P).x); (P).y = fmaf((S), (W).y, (P).y); \
                           (P).z = fmaf((S), (W).z, (P).z); (P).w = fmaf((S), (W).w, (P).w); } while(0)

// ================= L2-sync cooperative kernel (primary) =================
// 8 blocks per batch group; member m of group b is blockIdx = m*32 + b, so all
// members share blockIdx%8 == b%8 -> same XCD (perf-only assumption).
// Weights in registers (h2h slice 16xfloat4, x2h 2xfloat4, W_rff 32xfloat).
// Per-step hy exchange: each fp32 as two tagged dwords {16 payload | 16 tag},
// published BOTH via volatile u64 store (write-through -> shared L2, fast path)
// AND agent-scope atomic dword stores to the SAME address (MALL, correctness
// path). Readers poll volatile u64 (L2 hit if same XCD); after 4 misses they
// additionally poll via agent atomics. Tags self-validate either path.
// RFF for step t runs in the poll shadow of step t+1 (hyf double-buffered).
__global__ __launch_bounds__(TPB, 2) void coesn_l2(
    const float* __restrict__ x, const float* __restrict__ x2h,
    const float* __restrict__ h2h, const float* __restrict__ bias,
    const float* __restrict__ gam, const float* __restrict__ eps,
    const float* __restrict__ W_rff, unsigned long long* __restrict__ gbuf,
    float* __restrict__ out) {
  __shared__ __align__(16) float hyf[2][Hz];     // swizzled hy double buffer
  __shared__ __align__(16) float xb[2][Iz];      // x_t double buffer
  __shared__ __align__(16) float part[NMEM][64]; // [wave][col] partials

  const int b    = blockIdx.x & 31;
  const int m    = blockIdx.x >> 5;
  const int u    = threadIdx.x;
  const int c0   = m * 64;
  const int ksl  = u >> 4;       // 0..31: K-slice (16 h2h rows + 2 x2h rows)
  const int cg   = u & 15;       // float4 column group within 64-col slice
  const int wv   = u >> 6;       // wave id == owner-member of global column u
  const int lane = u & 63;
  const int rloc = u >> 4;       // RFF local row
  const int kseg = u & 15;       // RFF K segment

  // ---- weight slices into registers (one-time) ----
  float4 wreg[16];
  #pragma unroll
  for (int k = 0; k < 16; ++k)
    wreg[k] = *(const float4*)(h2h + (size_t)(ksl * 16 + k) * Hz + c0 + 4 * cg);
  float4 xreg[2];
  #pragma unroll
  for (int j = 0; j < 2; ++j)
    xreg[j] = *(const float4*)(x2h + (size_t)(ksl * 2 + j) * Hz + c0 + 4 * cg);
  float wr[32];
  {
    const float* wp = W_rff + (size_t)(m * 32 + rloc) * Hz + kseg * 32;
    #pragma unroll
    for (int j = 0; j < 32; ++j) wr[j] = wp[j];
  }

  float hy = 0.f, hz = 0.f, bu = 0.f, gu = 0.f, eu = 0.f;
  if (u < 64) { bu = bias[c0 + u]; gu = gam[c0 + u]; eu = eps[c0 + u]; }
  hyf[0][u] = 0.f;
  if (u < 16) ((float4*)xb[0])[u] = ((const float4*)(x + (size_t)b * Lz * Iz))[u];
  float zc = 0.f, zs = 0.f;
  __syncthreads();

  auto rff_acc = [&](const float* hsrc) {
    float acc = 0.f;
    #pragma unroll
    for (int i = 0; i < 8; ++i) {
      int q = kseg * 8 + i;
      float4 h4 = ((const float4*)hsrc)[q ^ ((q >> 3) & 7)];
      acc = fmaf(h4.x, wr[4 * i], acc);
      acc = fmaf(h4.y, wr[4 * i + 1], acc);
      acc = fmaf(h4.z, wr[4 * i + 2], acc);
      acc = fmaf(h4.w, wr[4 * i + 3], acc);
    }
    acc += __shfl_xor(acc, 1); acc += __shfl_xor(acc, 2);
    acc += __shfl_xor(acc, 4); acc += __shfl_xor(acc, 8);
    float sv, cv;
    __sincosf(acc, &sv, &cv);
    zc += cv; zs += sv;
  };

  for (int t = 0; t < Lz; ++t) {
    const int cur = t & 1, nxt = cur ^ 1;

    // ---- phase A: matvec partials from registers, hy(t) via LDS broadcast ----
    float hv[16];
    #pragma unroll
    for (int j = 0; j < 4; ++j) {
      int q = ksl * 4 + j;
      float4 h4 = ((const float4*)hyf[cur])[q ^ ((q >> 3) & 7)];
      hv[4 * j] = h4.x; hv[4 * j + 1] = h4.y; hv[4 * j + 2] = h4.z; hv[4 * j + 3] = h4.w;
    }
    float4 p = make_float4(0.f, 0.f, 0.f, 0.f);
    #pragma unroll
    for (int k = 0; k < 16; ++k) FMA4(p, hv[k], wreg[k]);
    {
      const float* xcur = xb[cur];
      FMA4(p, xcur[ksl * 2], xreg[0]);
      FMA4(p, xcur[ksl * 2 + 1], xreg[1]);
    }
    if (u < 16 && t + 1 < Lz)
      ((float4*)xb[nxt])[u] =
          ((const float4*)(x + ((size_t)b * Lz + (t + 1)) * Iz))[u];
    // reduce 4 K-slices within the wave (lanes l, l^16, l^32, l^48 share cg)
    p.x += __shfl_xor(p.x, 16); p.y += __shfl_xor(p.y, 16);
    p.z += __shfl_xor(p.z, 16); p.w += __shfl_xor(p.w, 16);
    p.x += __shfl_xor(p.x, 32); p.y += __shfl_xor(p.y, 32);
    p.z += __shfl_xor(p.z, 32); p.w += __shfl_xor(p.w, 32);
    if (lane < 16) ((float4*)part[wv])[lane] = p;
    __syncthreads();   // (1)

    const unsigned tag = (unsigned)(t + 1);
    unsigned long long* A = gbuf + ((size_t)nxt * Bz + b) * Hz;

    // ---- phase B: owners reduce + state update + dual publish ----
    if (u < 64) {
      float s = 0.f;
      #pragma unroll
      for (int w = 0; w < 8; ++w) s += part[w][u];
      s += bu;
      float e2 = __expf(s + s);                                   // e^{2s}
      float pre = 1.f - 2.f * __builtin_amdgcn_rcpf(e2 + 1.f);    // fast tanh
      float hzn = fmaf(DTz, pre - gu * hy - eu * hz, hz);
      hy = fmaf(DTz, hzn, hy);
      hz = hzn;
      unsigned bits = __float_as_uint(hy);
      unsigned ax = (bits & 0xffff0000u) | tag;
      unsigned ay = (bits << 16) | tag;
      *(volatile unsigned long long*)(A + c0 + u) =
          ((unsigned long long)ay << 32) | ax;                    // L2 fast path
      unsigned* Bd = (unsigned*)(A + c0 + u);
      __hip_atomic_store(Bd, ax, __ATOMIC_RELAXED, __HIP_MEMORY_SCOPE_AGENT);
      __hip_atomic_store(Bd + 1, ay, __ATOMIC_RELAXED, __HIP_MEMORY_SCOPE_AGENT);
      int q = (c0 + u) >> 2;
      hyf[nxt][(q ^ ((q >> 3) & 7)) * 4 + (u & 3)] = hy;          // local cols via LDS
    }

    // ---- phase E (poll shadow): RFF on hy(t) ----
    if (t > 0) rff_acc(hyf[cur]);

    // ---- phase D: poll remote columns (self-validating tags) ----
    if (wv != m) {
      unsigned ax, ay; int it = 0;
      for (;;) {
        unsigned long long v = *(volatile const unsigned long long*)(A + u);
        ax = (unsigned)v; ay = (unsigned)(v >> 32);
        if (!(((ax ^ tag) | (ay ^ tag)) & 0xffffu)) break;
        if (it >= 4) {
          const unsigned* Bd = (const unsigned*)(A + u);
          ax = __hip_atomic_load(Bd, __ATOMIC_RELAXED, __HIP_MEMORY_SCOPE_AGENT);
          ay = __hip_atomic_load(Bd + 1, __ATOMIC_RELAXED, __HIP_MEMORY_SCOPE_AGENT);
          if (!(((ax ^ tag) | (ay ^ tag)) & 0xffffu)) break;
        }
        if (++it > (1 << 20)) break;   // bail-out (never in practice)
      }
      int q = u >> 2;
      hyf[nxt][(q ^ ((q >> 3) & 7)) * 4 + (u & 3)] =
          __uint_as_float((ax & 0xffff0000u) | (ay >> 16));
    }
    __syncthreads();   // (2)
  }

  // final RFF term on hy(L) (loop accumulated hy(1)..hy(L-1)); Lz even -> hyf[0]
  rff_acc(hyf[0]);

  if (u < 64) out[(size_t)Bz * Hz + (size_t)b * Hz + c0 + u] = hy;
  if (kseg == 0) {
    const float sc = 0.0625f / 2048.f;   // (1/sqrt(256)) / L
    out[(size_t)b * Hz + m * 32 + rloc] = zc * sc;
    out[(size_t)b * Hz + HALFz + m * 32 + rloc] = zs * sc;
  }
}

// ================= single-block-per-batch fallback (proven R1) =================
__global__ __launch_bounds__(512) void coesn_scan_fb(
    const float* __restrict__ x, const float* __restrict__ x2h,
    const float* __restrict__ h2h, const float* __restrict__ bias,
    const float* __restrict__ gam, const float* __restrict__ eps,
    const float* __restrict__ W_rff, float* __restrict__ out) {
  const int b = blockIdx.x;
  const int u = threadIdx.x;
  __shared__ __align__(16) float hy_lds[Hz];
  __shared__ __align__(16) float x_lds[Iz];
  __shared__ float4 part[4][128];
  __shared__ float wx_lds[HALFz];

  float hy = 0.f, hz = 0.f, zsum = 0.f;
  const float bu = bias[u];
  const float gu = gam[u];
  const float eu = eps[u];

  const int kq = u >> 7;
  const int g  = u & 127;
  const int jj = u >> 2;
  const int ks = u & 3;

  const float4* __restrict__ H4 = (const float4*)h2h;
  const float4* __restrict__ X2 = (const float4*)x2h;
  const float4* __restrict__ W4 = (const float4*)W_rff;
  const float4* __restrict__ XG = (const float4*)x;
  const float4* hy4 = (const float4*)hy_lds;

  hy_lds[u] = 0.f;
  if (u < 16) ((float4*)x_lds)[u] = XG[(long)b * Lz * 16 + u];
  __syncthreads();

  for (int t = 0; t < Lz; ++t) {
    float4 p = make_float4(0.f, 0.f, 0.f, 0.f);
    {
      const float4* hp = (const float4*)&hy_lds[kq << 7];
      #pragma unroll 8
      for (int k4 = 0; k4 < 32; ++k4) {
        float4 hv = hp[k4];
        const float4* wr2 = &H4[(size_t)((kq << 7) + (k4 << 2)) * 128 + g];
        float4 w0 = wr2[0]; float4 w1 = wr2[128]; float4 w2 = wr2[256]; float4 w3 = wr2[384];
        FMA4(p, hv.x, w0); FMA4(p, hv.y, w1); FMA4(p, hv.z, w2); FMA4(p, hv.w, w3);
      }
      const float4* xp = (const float4*)&x_lds[kq << 4];
      #pragma unroll
      for (int k4 = 0; k4 < 4; ++k4) {
        float4 xv = xp[k4];
        const float4* wr2 = &X2[(size_t)((kq << 4) + (k4 << 2)) * 128 + g];
        float4 w0 = wr2[0]; float4 w1 = wr2[128]; float4 w2 = wr2[256]; float4 w3 = wr2[384];
        FMA4(p, xv.x, w0); FMA4(p, xv.y, w1); FMA4(p, xv.z, w2); FMA4(p, xv.w, w3);
      }
    }
    part[kq][g] = p;
    __syncthreads();
    {
      const float* pp = (const float*)part;
      float s = (pp[u] + pp[512 + u]) + (pp[1024 + u] + pp[1536 + u]);
      float pre = tanhf(s + bu);
      float hzn = fmaf(DTz, pre - gu * hy - eu * hz, hz);
      hy = fmaf(DTz, hzn, hy);
      hz = hzn;
      hy_lds[u] = hy;
      if (u < 16 && t + 1 < Lz)
        ((float4*)x_lds)[u] = XG[((long)b * Lz + (t + 1)) * 16 + u];
    }
    __syncthreads();
    {
      float4 acc0 = make_float4(0.f,0.f,0.f,0.f), acc1 = make_float4(0.f,0.f,0.f,0.f);
      #pragma unroll 4
      for (int it = 0; it < 32; ++it) {
        int k4 = (it << 2) + ks;
        float4 hv = hy4[k4];
        float4 w0 = W4[(size_t)jj * 128 + k4];
        float4 w1 = W4[(size_t)(jj + 128) * 128 + k4];
        acc0.x = fmaf(hv.x, w0.x, acc0.x); acc0.y = fmaf(hv.y, w0.y, acc0.y);
        acc0.z = fmaf(hv.z, w0.z, acc0.z); acc0.w = fmaf(hv.w, w0.w, acc0.w);
        acc1.x = fmaf(hv.x, w1.x, acc1.x); acc1.y = fmaf(hv.y, w1.y, acc1.y);
        acc1.z = fmaf(hv.z, w1.z, acc1.z); acc1.w = fmaf(hv.w, w1.w, acc1.w);
      }
      float a0 = (acc0.x + acc0.y) + (acc0.z + acc0.w);
      float a1 = (acc1.x + acc1.y) + (acc1.z + acc1.w);
      a0 += __shfl_xor(a0, 1); a0 += __shfl_xor(a0, 2);
      a1 += __shfl_xor(a1, 1); a1 += __shfl_xor(a1, 2);
      if (ks == 0) { wx_lds[jj] = a0; wx_lds[jj + 128] = a1; }
    }
    __syncthreads();
    {
      float v = wx_lds[u & 255];
      zsum += (u < HALFz) ? cosf(v) : sinf(v);
    }
  }
  out[(long)b * Hz + u] = zsum * (0.0625f / 2048.f);
  out[(long)Bz * Hz + (long)b * Hz + u] = hy;
}

extern "C" void kernel_launch(void* const* d_in, const int* in_sizes, int n_in,
                              void* d_out, int out_size, void* d_ws, size_t ws_size,
                              hipStream_t stream) {
  const float* x    = (const float*)d_in[0];
  const float* x2h  = (const float*)d_in[1];
  const float* h2h  = (const float*)d_in[2];
  const float* bias = (const float*)d_in[3];
  const float* gam  = (const float*)d_in[4];
  const float* eps  = (const float*)d_in[5];
  const float* wrff = (const float*)d_in[6];
  float* out = (float*)d_out;

  // ws: 2 parities x 32 groups x 512 cols x 8B = 256 KB tagged exchange
  const size_t WS_NEED = (size_t)2 * Bz * Hz * sizeof(unsigned long long);
  if (ws_size >= WS_NEED) {
    unsigned long long* gbuf = (unsigned long long*)d_ws;
    hipMemsetAsync(d_ws, 0, WS_NEED, stream);
    void* args[] = { (void*)&x, (void*)&x2h, (void*)&h2h, (void*)&bias,
                     (void*)&gam, (void*)&eps, (void*)&wrff,
                     (void*)&gbuf, (void*)&out };
    hipError_t e = hipLaunchCooperativeKernel((const void*)coesn_l2,
                                              dim3(Bz * NMEM), dim3(TPB),
                                              args, 0, stream);
    if (e == hipSuccess) return;
  }
  coesn_scan_fb<<<Bz, 512, 0, stream>>>(x, x2h, h2h, bias, gam, eps, wrff, out);
}

// Round 6
// 3412.267 us; speedup vs baseline: 1.2496x; 1.2496x over previous
//
#include <hip/hip_runtime.h>
#include <math.h>

#define Bz 32
#define Lz 2048
#define Iz 64
#define Hz 512
#define HALFz 256
#define DTz 0.05f
#define NMEM 8
#define TPB 512

typedef unsigned long long u64;

__device__ __forceinline__ bool tagok(u64 v, unsigned tag) {
  u64 want = (u64)tag | ((u64)tag << 48);
  return ((v ^ want) & 0xFFFF00000000FFFFull) == 0ull;
}
__device__ __forceinline__ u64 packv(float f, unsigned tag) {
  return (u64)tag | ((u64)__float_as_uint(f) << 16) | ((u64)tag << 48);
}
__device__ __forceinline__ float unpackv(u64 v) {
  return __uint_as_float((unsigned)(v >> 16));
}

// ================= XCD-L2 exchange cooperative kernel (primary) =================
// 8 blocks per batch group; member m of group b is blockIdx = m*32 + b, so all
// members share blockIdx%8 == b%8 -> same XCD (perf-only; Y-path covers other
// mappings). Weights fully register-resident. One barrier per step.
// Per wave: 8 full-K output columns; lane covers 8 K-rows x 8 cols, reduced by
// a 10-shuffle fold so every lane holds its column's full sum (divergence-free
// update; lanes 0-7 publish). Exchange: tagged u64 per column, dual-published
// to X (plain volatile store -> shared L2) and Y (agent atomic -> MALL),
// disjoint buffers. Readers poll X; after 2 misses also poll Y. RFF for step t
// runs in the poll shadow of step t+1.
// NOTE (R5 bug): rff_acc's shfl_xor chain already fully reduces wx into every
// lane of the 16-lane kseg group, so zc/zs are COMPLETE per-lane. Do NOT
// reduce them again at the end (that multiplied mu by 16).
__global__ __launch_bounds__(TPB, 2) void coesn_x2(
    const float* __restrict__ x, const float* __restrict__ x2h,
    const float* __restrict__ h2h, const float* __restrict__ bias,
    const float* __restrict__ gam, const float* __restrict__ eps,
    const float* __restrict__ W_rff, u64* __restrict__ Xb,
    u64* __restrict__ Yb, float* __restrict__ out) {
  __shared__ __align__(16) float hyf[2][Hz];   // swizzled hy double buffer
  __shared__ __align__(16) float xb[2][Iz];    // x_t double buffer

  const int b  = blockIdx.x & 31;
  const int m  = blockIdx.x >> 5;
  const int u  = threadIdx.x;
  const int w  = u >> 6;          // wave id; also owner-member of global col u
  const int l  = u & 63;
  const int c0 = m * 64;
  const int j  = ((l & 1) << 2) | (l & 2) | ((l >> 2) & 1);  // fold col map
  const int mycol = c0 + w * 8 + j;        // column this lane's state tracks
  const int rloc = u >> 4, kseg = u & 15;  // RFF mapping

  // ---- weights into registers (one-time) ----
  float wreg[8][8];   // [K-row r'][col jj]: h2h[8l+r'][c0+8w+jj]
  {
    const float* hrow = h2h + (size_t)(8 * l) * Hz + c0 + 8 * w;
    #pragma unroll
    for (int r = 0; r < 8; ++r) {
      float4 v0 = *(const float4*)(hrow + (size_t)r * Hz);
      float4 v1 = *(const float4*)(hrow + (size_t)r * Hz + 4);
      wreg[r][0] = v0.x; wreg[r][1] = v0.y; wreg[r][2] = v0.z; wreg[r][3] = v0.w;
      wreg[r][4] = v1.x; wreg[r][5] = v1.y; wreg[r][6] = v1.z; wreg[r][7] = v1.w;
    }
  }
  float xreg[8];      // x2h[l][c0+8w+jj]
  {
    float4 v0 = *(const float4*)(x2h + (size_t)l * Hz + c0 + 8 * w);
    float4 v1 = *(const float4*)(x2h + (size_t)l * Hz + c0 + 8 * w + 4);
    xreg[0] = v0.x; xreg[1] = v0.y; xreg[2] = v0.z; xreg[3] = v0.w;
    xreg[4] = v1.x; xreg[5] = v1.y; xreg[6] = v1.z; xreg[7] = v1.w;
  }
  float wr[32];       // W_rff[m*32+rloc][kseg*32 .. +32)
  {
    const float* wp = W_rff + (size_t)(m * 32 + rloc) * Hz + kseg * 32;
    #pragma unroll
    for (int i = 0; i < 32; ++i) wr[i] = wp[i];
  }

  const float bu = bias[mycol];
  const float gu = gam[mycol];
  const float eu = eps[mycol];
  float hy = 0.f, hz = 0.f, zc = 0.f, zs = 0.f;
  hyf[0][u] = 0.f;
  if (u < 16) ((float4*)xb[0])[u] = ((const float4*)(x + (size_t)b * Lz * Iz))[u];
  __syncthreads();

  auto rff_acc = [&](const float* hsrc) {
    float acc = 0.f;
    const float4* hp = (const float4*)hsrc;
    #pragma unroll
    for (int i = 0; i < 8; ++i) {
      int q = kseg * 8 + i;
      float4 h4 = hp[q ^ ((q >> 3) & 7)];
      acc = fmaf(h4.x, wr[4 * i], acc);
      acc = fmaf(h4.y, wr[4 * i + 1], acc);
      acc = fmaf(h4.z, wr[4 * i + 2], acc);
      acc = fmaf(h4.w, wr[4 * i + 3], acc);
    }
    // full wx lands in EVERY lane of the 16-lane group
    acc += __shfl_xor(acc, 1); acc += __shfl_xor(acc, 2);
    acc += __shfl_xor(acc, 4); acc += __shfl_xor(acc, 8);
    float sv, cv;
    __sincosf(acc, &sv, &cv);
    zc += cv; zs += sv;   // complete values, identical across the 16 lanes
  };

  for (int t = 0; t < Lz; ++t) {
    const int cur = t & 1, nxt = cur ^ 1;

    // ---- x(t+1) prefetch ----
    if (u < 16 && t + 1 < Lz)
      ((float4*)xb[nxt])[u] =
          ((const float4*)(x + ((size_t)b * Lz + (t + 1)) * Iz))[u];

    // ---- matvec: lane covers K-rows [8l,8l+8) for cols c0+8w..+8 ----
    float hv[8];
    {
      const float4* hp = (const float4*)hyf[cur];
      int q0 = 2 * l, q1 = 2 * l + 1;
      float4 h0 = hp[q0 ^ ((q0 >> 3) & 7)];
      float4 h1 = hp[q1 ^ ((q1 >> 3) & 7)];
      hv[0] = h0.x; hv[1] = h0.y; hv[2] = h0.z; hv[3] = h0.w;
      hv[4] = h1.x; hv[5] = h1.y; hv[6] = h1.z; hv[7] = h1.w;
    }
    float a[8] = {0.f, 0.f, 0.f, 0.f, 0.f, 0.f, 0.f, 0.f};
    #pragma unroll
    for (int r = 0; r < 8; ++r) {
      float h = hv[r];
      #pragma unroll
      for (int c = 0; c < 8; ++c) a[c] = fmaf(h, wreg[r][c], a[c]);
    }
    {
      float xv = xb[cur][l];
      #pragma unroll
      for (int c = 0; c < 8; ++c) a[c] = fmaf(xv, xreg[c], a[c]);
    }
    // ---- 10-shuffle fold: lane ends with full sum for col j(l) ----
    #pragma unroll
    for (int i = 0; i < 4; ++i) {
      float snd = (l & 1) ? a[i] : a[i + 4];
      float rcv = __shfl_xor(snd, 1);
      a[i] = ((l & 1) ? a[i + 4] : a[i]) + rcv;
    }
    #pragma unroll
    for (int i = 0; i < 2; ++i) {
      float snd = (l & 2) ? a[i] : a[i + 2];
      float rcv = __shfl_xor(snd, 2);
      a[i] = ((l & 2) ? a[i + 2] : a[i]) + rcv;
    }
    float s;
    {
      float snd = (l & 4) ? a[0] : a[1];
      float rcv = __shfl_xor(snd, 4);
      s = ((l & 4) ? a[1] : a[0]) + rcv;
    }
    s += __shfl_xor(s, 8); s += __shfl_xor(s, 16); s += __shfl_xor(s, 32);

    // ---- state update (divergence-free; redundant across lane-octs) ----
    s += bu;
    float e2 = __expf(s + s);
    float pre = 1.f - 2.f * __builtin_amdgcn_rcpf(e2 + 1.f);   // fast tanh
    float hzn = fmaf(DTz, pre - gu * hy - eu * hz, hz);
    hy = fmaf(DTz, hzn, hy);
    hz = hzn;

    const unsigned tag = (unsigned)(t + 1);
    u64* XA = Xb + ((size_t)nxt * Bz + b) * Hz;
    u64* YA = Yb + ((size_t)nxt * Bz + b) * Hz;

    if (l < 8) {
      u64 pv = packv(hy, tag);
      *(volatile u64*)(XA + mycol) = pv;                        // L2 fast path
      __hip_atomic_store(YA + mycol, pv, __ATOMIC_RELAXED,
                         __HIP_MEMORY_SCOPE_AGENT);             // MALL safe path
      int q = mycol >> 2;
      hyf[nxt][(q ^ ((q >> 3) & 7)) * 4 + (mycol & 3)] = hy;    // local cols
    }

    // ---- RFF on hy(t) in the exchange shadow ----
    if (t > 0) rff_acc(hyf[cur]);

    // ---- poll remote columns ----
    if (w != m) {
      u64 v; int it = 0;
      for (;;) {
        v = *(volatile const u64*)(XA + u);
        if (tagok(v, tag)) break;
        if (it >= 2) {
          v = __hip_atomic_load(YA + u, __ATOMIC_RELAXED,
                                __HIP_MEMORY_SCOPE_AGENT);
          if (tagok(v, tag)) break;
        }
        if (++it > (1 << 20)) break;   // safety bail (never in practice)
      }
      int q = u >> 2;
      hyf[nxt][(q ^ ((q >> 3) & 7)) * 4 + (u & 3)] = unpackv(v);
    }
    __syncthreads();
  }

  // final RFF term on hy(Lz) (loop covered hy(1)..hy(Lz-1)); Lz even -> hyf[0]
  rff_acc(hyf[0]);

  if (l < 8) out[(size_t)Bz * Hz + (size_t)b * Hz + mycol] = hy;
  // zc/zs are already complete in every lane (see NOTE) — just write once.
  if (kseg == 0) {
    const float sc = 0.0625f / 2048.f;   // (1/sqrt(256)) / L
    out[(size_t)b * Hz + m * 32 + rloc] = zc * sc;
    out[(size_t)b * Hz + HALFz + m * 32 + rloc] = zs * sc;
  }
}

// ================= single-block-per-batch fallback (proven R1) =================
#define FMA4(P, S, W) do { (P).x = fmaf((S), (W).x, (P).x); (P).y = fmaf((S), (W).y, (P).y); \
                           (P).z = fmaf((S), (W).z, (P).z); (P).w = fmaf((S), (W).w, (P).w); } while(0)

__global__ __launch_bounds__(512) void coesn_scan_fb(
    const float* __restrict__ x, const float* __restrict__ x2h,
    const float* __restrict__ h2h, const float* __restrict__ bias,
    const float* __restrict__ gam, const float* __restrict__ eps,
    const float* __restrict__ W_rff, float* __restrict__ out) {
  const int b = blockIdx.x;
  const int u = threadIdx.x;
  __shared__ __align__(16) float hy_lds[Hz];
  __shared__ __align__(16) float x_lds[Iz];
  __shared__ float4 part[4][128];
  __shared__ float wx_lds[HALFz];

  float hy = 0.f, hz = 0.f, zsum = 0.f;
  const float bu = bias[u];
  const float gu = gam[u];
  const float eu = eps[u];

  const int kq = u >> 7;
  const int g  = u & 127;
  const int jj = u >> 2;
  const int ks = u & 3;

  const float4* __restrict__ H4 = (const float4*)h2h;
  const float4* __restrict__ X2 = (const float4*)x2h;
  const float4* __restrict__ W4 = (const float4*)W_rff;
  const float4* __restrict__ XG = (const float4*)x;
  const float4* hy4 = (const float4*)hy_lds;

  hy_lds[u] = 0.f;
  if (u < 16) ((float4*)x_lds)[u] = XG[(long)b * Lz * 16 + u];
  __syncthreads();

  for (int t = 0; t < Lz; ++t) {
    float4 p = make_float4(0.f, 0.f, 0.f, 0.f);
    {
      const float4* hp = (const float4*)&hy_lds[kq << 7];
      #pragma unroll 8
      for (int k4 = 0; k4 < 32; ++k4) {
        float4 hv = hp[k4];
        const float4* wr2 = &H4[(size_t)((kq << 7) + (k4 << 2)) * 128 + g];
        float4 w0 = wr2[0]; float4 w1 = wr2[128]; float4 w2 = wr2[256]; float4 w3 = wr2[384];
        FMA4(p, hv.x, w0); FMA4(p, hv.y, w1); FMA4(p, hv.z, w2); FMA4(p, hv.w, w3);
      }
      const float4* xp = (const float4*)&x_lds[kq << 4];
      #pragma unroll
      for (int k4 = 0; k4 < 4; ++k4) {
        float4 xv = xp[k4];
        const float4* wr2 = &X2[(size_t)((kq << 4) + (k4 << 2)) * 128 + g];
        float4 w0 = wr2[0]; float4 w1 = wr2[128]; float4 w2 = wr2[256]; float4 w3 = wr2[384];
        FMA4(p, xv.x, w0); FMA4(p, xv.y, w1); FMA4(p, xv.z, w2); FMA4(p, xv.w, w3);
      }
    }
    part[kq][g] = p;
    __syncthreads();
    {
      const float* pp = (const float*)part;
      float s = (pp[u] + pp[512 + u]) + (pp[1024 + u] + pp[1536 + u]);
      float pre = tanhf(s + bu);
      float hzn = fmaf(DTz, pre - gu * hy - eu * hz, hz);
      hy = fmaf(DTz, hzn, hy);
      hz = hzn;
      hy_lds[u] = hy;
      if (u < 16 && t + 1 < Lz)
        ((float4*)x_lds)[u] = XG[((long)b * Lz + (t + 1)) * 16 + u];
    }
    __syncthreads();
    {
      float4 acc0 = make_float4(0.f,0.f,0.f,0.f), acc1 = make_float4(0.f,0.f,0.f,0.f);
      #pragma unroll 4
      for (int it = 0; it < 32; ++it) {
        int k4 = (it << 2) + ks;
        float4 hv = hy4[k4];
        float4 w0 = W4[(size_t)jj * 128 + k4];
        float4 w1 = W4[(size_t)(jj + 128) * 128 + k4];
        acc0.x = fmaf(hv.x, w0.x, acc0.x); acc0.y = fmaf(hv.y, w0.y, acc0.y);
        acc0.z = fmaf(hv.z, w0.z, acc0.z); acc0.w = fmaf(hv.w, w0.w, acc0.w);
        acc1.x = fmaf(hv.x, w1.x, acc1.x); acc1.y = fmaf(hv.y, w1.y, acc1.y);
        acc1.z = fmaf(hv.z, w1.z, acc1.z); acc1.w = fmaf(hv.w, w1.w, acc1.w);
      }
      float a0 = (acc0.x + acc0.y) + (acc0.z + acc0.w);
      float a1 = (acc1.x + acc1.y) + (acc1.z + acc1.w);
      a0 += __shfl_xor(a0, 1); a0 += __shfl_xor(a0, 2);
      a1 += __shfl_xor(a1, 1); a1 += __shfl_xor(a1, 2);
      if (ks == 0) { wx_lds[jj] = a0; wx_lds[jj + 128] = a1; }
    }
    __syncthreads();
    {
      float v = wx_lds[u & 255];
      zsum += (u < HALFz) ? cosf(v) : sinf(v);
    }
  }
  out[(long)b * Hz + u] = zsum * (0.0625f / 2048.f);
  out[(long)Bz * Hz + (long)b * Hz + u] = hy;
}

extern "C" void kernel_launch(void* const* d_in, const int* in_sizes, int n_in,
                              void* d_out, int out_size, void* d_ws, size_t ws_size,
                              hipStream_t stream) {
  const float* x    = (const float*)d_in[0];
  const float* x2h  = (const float*)d_in[1];
  const float* h2h  = (const float*)d_in[2];
  const float* bias = (const float*)d_in[3];
  const float* gam  = (const float*)d_in[4];
  const float* eps  = (const float*)d_in[5];
  const float* wrff = (const float*)d_in[6];
  float* out = (float*)d_out;

  // ws: X buffer 256KB (2 parity x 32 grp x 512 x u64) + Y buffer 256KB
  const size_t NEX = (size_t)2 * Bz * Hz;               // u64 elements per buffer
  const size_t WS_NEED = 2 * NEX * sizeof(u64);         // 512 KB
  if (ws_size >= WS_NEED) {
    u64* Xb = (u64*)d_ws;
    u64* Yb = Xb + NEX;
    hipMemsetAsync(d_ws, 0, WS_NEED, stream);
    void* args[] = { (void*)&x, (void*)&x2h, (void*)&h2h, (void*)&bias,
                     (void*)&gam, (void*)&eps, (void*)&wrff,
                     (void*)&Xb, (void*)&Yb, (void*)&out };
    hipError_t e = hipLaunchCooperativeKernel((const void*)coesn_x2,
                                              dim3(Bz * NMEM), dim3(TPB),
                                              args, 0, stream);
    if (e == hipSuccess) return;
  }
  coesn_scan_fb<<<Bz, 512, 0, stream>>>(x, x2h, h2h, bias, gam, eps, wrff, out);
}